// Round 10
// baseline (675.094 us; speedup 1.0000x reference)
//
#include <hip/hip_runtime.h>
#include <math.h>

#define TT 256
#define NI 29
#define HH 128
#define NC 29
#define ROWS 16
#define PSTR 136   // fp16 plane stride (halfs); 272 B rows
#define BB 2048L
#define BT (BB * TT)
#define WS_NEED (BT * HH * 2)   // 134,217,728 B fp16 [B*T][H]: xp, overwritten by h

typedef _Float16 f16x8 __attribute__((ext_vector_type(8)));
typedef _Float16 f16x4 __attribute__((ext_vector_type(4)));
typedef float f32x4 __attribute__((ext_vector_type(4)));

// tanh(x) = 1 - 2/(e^{2x}+1); e^{2x} = 2^{2x*log2(e)}. Graceful at +-inf.
__device__ __forceinline__ float fast_tanh(float x) {
    float e = __builtin_amdgcn_exp2f(x * 2.885390081777927f);
    return 1.0f - 2.0f * __builtin_amdgcn_rcpf(e + 1.0f);
}

__device__ __forceinline__ f16x8 cvt8(const float4& a, const float4& b) {
    f16x8 r;
    r[0] = (_Float16)a.x; r[1] = (_Float16)a.y;
    r[2] = (_Float16)a.z; r[3] = (_Float16)a.w;
    r[4] = (_Float16)b.x; r[5] = (_Float16)b.y;
    r[6] = (_Float16)b.z; r[7] = (_Float16)b.w;
    return r;
}

__device__ __forceinline__ f16x4 tanh4(const f32x4& a) {
    f16x4 r;
#pragma unroll
    for (int q = 0; q < 4; ++q) r[q] = (_Float16)fast_tanh(a[q]);
    return r;
}

__device__ __forceinline__ f16x8 pack44(const f16x4& a, const f16x4& b) {
    f16x8 r;
    r[0] = a[0]; r[1] = a[1]; r[2] = a[2]; r[3] = a[3];
    r[4] = b[0]; r[5] = b[1]; r[6] = b[2]; r[7] = b[3];
    return r;
}

// zero-pad tail load (x rows for xp kernel): i = 8g..8g+7
__device__ __forceinline__ void load_x0(const float* p, int g, float4& a, float4& b) {
    a = *(const float4*)p;
    if (g < 3) {
        b = *(const float4*)(p + 4);
    } else {
        b.x = p[4]; b.y = 0.f; b.z = 0.f; b.w = 0.f;
    }
}

// bias-column load (enc chain x~ = [x(29), 1, 0, 0])
__device__ __forceinline__ void load_xe(const float* p, int g, float4& a, float4& b) {
    a = *(const float4*)p;
    if (g < 3) {
        b = *(const float4*)(p + 4);
    } else {
        b.x = p[4]; b.y = 1.0f; b.z = 0.f; b.w = 0.f;
    }
}

#define MFMA16(A, B, C) __builtin_amdgcn_mfma_f32_16x16x32_f16((A), (B), (C), 0, 0, 0)

// J-permutation (R8/R9-verified): lane(m,g), acc a, reg q produce
// j = 32w + 4a + 8g + q; packed [a0q0..3, a1q0..3] = h[32w+8g .. +8) ==
// this lane's own B-slice s=w. A-frags loaded at rows J(a,m) =
// 32w + 4a + 8*(m>>2) + (m&3); consumption order k: slice s=(w+k)&3.
__device__ __forceinline__ void load_rnn_W(
    const float* __restrict__ Wih, const float* __restrict__ Whh,
    const float* __restrict__ bih, const float* __restrict__ bhh,
    int w, int m, int g, f16x8 (&AwO)[2][4], f16x8 (&AXO)[2])
{
#pragma unroll
    for (int a = 0; a < 2; ++a) {
        const int j = 32 * w + 4 * a + 8 * (m >> 2) + (m & 3);
#pragma unroll
        for (int k = 0; k < 4; ++k) {
            const int s = (w + k) & 3;
            const float* p = Whh + j * HH + 32 * s + 8 * g;
            AwO[a][k] = cvt8(*(const float4*)p, *(const float4*)(p + 4));
        }
        f16x8 ax;
#pragma unroll
        for (int e = 0; e < 8; ++e) {
            int kk = 8 * g + e;
            float v = (kk < NI) ? Wih[j * NI + kk]
                                : (kk == NI ? bih[j] + bhh[j] : 0.f);
            ax[e] = (_Float16)v;
        }
        AXO[a] = ax;
    }
}

// ---------------------------------------------------------------------------
// xp kernel: xp[bt][j] = Wih[j,:]·x[bt,:] + bih[j] + bhh[j]   (fp16)
// ---------------------------------------------------------------------------
__launch_bounds__(256)
__global__ void xp_kernel(const float* __restrict__ x,     // [B*T, NI]
                          const float* __restrict__ Wih,   // [H, NI]
                          const float* __restrict__ bih,
                          const float* __restrict__ bhh,
                          _Float16* __restrict__ xp)       // [B*T, H]
{
    const int tid  = threadIdx.x;
    const int lane = tid & 63;
    const int wv   = tid >> 6;
    const int m    = lane & 15;
    const int g    = lane >> 4;
    const long bt0 = ((long)blockIdx.x * 4 + wv) * 16;

    f16x8 A[8];
#pragma unroll
    for (int jt = 0; jt < 8; ++jt) {
        float4 v0, v1;
        load_x0(Wih + (16 * jt + m) * NI + 8 * g, g, v0, v1);
        A[jt] = cvt8(v0, v1);
    }
    float4 u0, u1;
    load_x0(x + (bt0 + m) * NI + 8 * g, g, u0, u1);
    f16x8 Bx = cvt8(u0, u1);

    const f32x4 z = {0.f, 0.f, 0.f, 0.f};
    f32x4 acc[8];
#pragma unroll
    for (int jt = 0; jt < 8; ++jt)
        acc[jt] = MFMA16(A[jt], Bx, z);

#pragma unroll
    for (int jt = 0; jt < 8; ++jt) {
        f16x4 o;
#pragma unroll
        for (int q = 0; q < 4; ++q) {
            int j = 16 * jt + 4 * g + q;
            o[q] = (_Float16)(acc[jt][q] + bih[j] + bhh[j]);
        }
        *(f16x4*)(xp + (bt0 + m) * HH + 16 * jt + 4 * g) = o;
    }
}

// ---------------------------------------------------------------------------
// FC kernel: out[bt][c] = fcW[c,:]·h[bt,:] + fcb[c], h fp16 from ws
// ---------------------------------------------------------------------------
__launch_bounds__(256)
__global__ void fc_kernel(const _Float16* __restrict__ hws,  // [B*T, H]
                          const float* __restrict__ fcW,     // [NC, H]
                          const float* __restrict__ fcb,
                          float* __restrict__ out)           // [B*T, NC]
{
    const int tid  = threadIdx.x;
    const int lane = tid & 63;
    const int wv   = tid >> 6;
    const int m    = lane & 15;
    const int g    = lane >> 4;
    const long bt0 = ((long)blockIdx.x * 4 + wv) * 16;

    f16x8 A0[4], A1[4];
#pragma unroll
    for (int s = 0; s < 4; ++s) {
        f16x8 a0, a1;
        const int c1 = 16 + m;
#pragma unroll
        for (int e = 0; e < 8; ++e) {
            int k = 32 * s + 8 * g + e;
            a0[e] = (_Float16)fcW[m * HH + k];
            a1[e] = (c1 < NC) ? (_Float16)fcW[c1 * HH + k] : (_Float16)0.f;
        }
        A0[s] = a0; A1[s] = a1;
    }
    f16x8 Bh[4];
#pragma unroll
    for (int s = 0; s < 4; ++s)
        Bh[s] = *(const f16x8*)(hws + (bt0 + m) * HH + 32 * s + 8 * g);

    const f32x4 z = {0.f, 0.f, 0.f, 0.f};
    f32x4 f0 = MFMA16(A0[0], Bh[0], z);
    f32x4 f1 = MFMA16(A1[0], Bh[0], z);
    f0 = MFMA16(A0[1], Bh[1], f0);
    f1 = MFMA16(A1[1], Bh[1], f1);
    f0 = MFMA16(A0[2], Bh[2], f0);
    f1 = MFMA16(A1[2], Bh[2], f1);
    f0 = MFMA16(A0[3], Bh[3], f0);
    f1 = MFMA16(A1[3], Bh[3], f1);

    float* op = out + (bt0 + m) * NC;
#pragma unroll
    for (int q = 0; q < 4; ++q) {
        op[4 * g + q] = f0[q] + fcb[4 * g + q];
        int c = 16 + 4 * g + q;
        if (c < NC) op[c] = f1[q] + fcb[c];
    }
}

// --------------------------- chain step macros -----------------------------
// STEPE: enc (and fallback dec): BX via load_xe (bias col), AX MFMAs.
#define STEPE(CUR, XA, XB, TV, DECF)                                          \
  {                                                                           \
    f16x8 rd0 = *(const f16x8*)&planes[CUR][m][rb1];                          \
    f16x8 rd1 = *(const f16x8*)&planes[CUR][m][rb2];                          \
    f16x8 rd2 = *(const f16x8*)&planes[CUR][m][rb3];                          \
    f16x8 BX = cvt8(XA, XB);                                                  \
    if ((TV) + 2 < TT) load_xe(xrow + ((TV) + 2) * NI, g, XA, XB);            \
    f32x4 ac0 = MFMA16(AXO[0], BX, zc);                                       \
    f32x4 ac1 = MFMA16(AXO[1], BX, zc);                                       \
    ac0 = MFMA16(AwO[0][0], own, ac0);  ac1 = MFMA16(AwO[1][0], own, ac1);    \
    ac0 = MFMA16(AwO[0][1], rd0, ac0);  ac1 = MFMA16(AwO[1][1], rd0, ac1);    \
    ac0 = MFMA16(AwO[0][2], rd1, ac0);  ac1 = MFMA16(AwO[1][2], rd1, ac1);    \
    ac0 = MFMA16(AwO[0][3], rd2, ac0);  ac1 = MFMA16(AwO[1][3], rd2, ac1);    \
    if ((DECF) && w >= 2 && (TV) > 0) {                                       \
      f32x4 f0 = MFMA16(AfcO[0], own, zc);                                    \
      f0 = MFMA16(AfcO[1], rd0, f0);                                          \
      f0 = MFMA16(AfcO[2], rd1, f0);                                          \
      f0 = MFMA16(AfcO[3], rd2, f0);                                          \
      float* op = outp + (long)((TV) - 1) * NC + cbase;                       \
      _Pragma("unroll") for (int q = 0; q < 4; ++q)                           \
        if (cbase + q < NC) op[q] = f0[q] + fcbv[q];                          \
    }                                                                         \
    own = pack44(tanh4(ac0), tanh4(ac1));                                     \
    *(f16x8*)&planes[(CUR) ^ 1][m][wr_off] = own;                             \
    asm volatile("s_waitcnt lgkmcnt(0)" ::: "memory");                        \
    __builtin_amdgcn_s_barrier();                                             \
    __builtin_amdgcn_sched_barrier(0);                                        \
  }

// STEPD: fast dec: acc init from xp (bias already folded), h dumped to ws.
#define STEPD(CUR, XQ, TV)                                                    \
  {                                                                           \
    f16x8 rd0 = *(const f16x8*)&planes[CUR][m][rb1];                          \
    f16x8 rd1 = *(const f16x8*)&planes[CUR][m][rb2];                          \
    f16x8 rd2 = *(const f16x8*)&planes[CUR][m][rb3];                          \
    f32x4 ac0 = {(float)XQ[0], (float)XQ[1], (float)XQ[2], (float)XQ[3]};     \
    f32x4 ac1 = {(float)XQ[4], (float)XQ[5], (float)XQ[6], (float)XQ[7]};     \
    if ((TV) + 4 < TT) XQ = *(const f16x8*)(xh + ((TV) + 4) * HH);            \
    ac0 = MFMA16(AwO[0][0], own, ac0);  ac1 = MFMA16(AwO[1][0], own, ac1);    \
    ac0 = MFMA16(AwO[0][1], rd0, ac0);  ac1 = MFMA16(AwO[1][1], rd0, ac1);    \
    ac0 = MFMA16(AwO[0][2], rd1, ac0);  ac1 = MFMA16(AwO[1][2], rd1, ac1);    \
    ac0 = MFMA16(AwO[0][3], rd2, ac0);  ac1 = MFMA16(AwO[1][3], rd2, ac1);    \
    own = pack44(tanh4(ac0), tanh4(ac1));                                     \
    *(f16x8*)(xh + (long)(TV) * HH) = own;                                    \
    *(f16x8*)&planes[(CUR) ^ 1][m][wr_off] = own;                             \
    asm volatile("s_waitcnt lgkmcnt(0)" ::: "memory");                        \
    __builtin_amdgcn_s_barrier();                                             \
    __builtin_amdgcn_sched_barrier(0);                                        \
  }

// 128 blocks x 256 threads (4 waves / 4 SIMDs). Wave w owns j [32w,32w+32):
// per step 8 rec MFMAs, 8 tanh, 3 foreign-slice b128 reads, 1 b128 write.
// Symmetric waves; FC and x-projection live outside the serial chain (XP=1).
template <int XP>
__launch_bounds__(256, 1)
__global__ void seq2seq_chain(const float* __restrict__ enc_in,
                              const float* __restrict__ h0p,   // [1,B,H]
                              const float* __restrict__ dec_in,
                              const float* __restrict__ eWih,
                              const float* __restrict__ eWhh,
                              const float* __restrict__ ebih,
                              const float* __restrict__ ebhh,
                              const float* __restrict__ dWih,
                              const float* __restrict__ dWhh,
                              const float* __restrict__ dbih,
                              const float* __restrict__ dbhh,
                              const float* __restrict__ fcW,
                              const float* __restrict__ fcb,
                              _Float16* __restrict__ hws,      // [B*T,H] xp->h
                              float* __restrict__ out)
{
    __shared__ __align__(16) _Float16 planes[2][ROWS][PSTR];

    const int tid  = threadIdx.x;
    const int w    = tid >> 6;
    const int lane = tid & 63;
    const int m    = lane & 15;
    const int g    = lane >> 4;
    const int b0   = blockIdx.x * ROWS;

    const int wr_off = 32 * w + 8 * g;
    const int rb1 = 32 * ((w + 1) & 3) + 8 * g;
    const int rb2 = 32 * ((w + 2) & 3) + 8 * g;
    const int rb3 = 32 * ((w + 3) & 3) + 8 * g;

    const f32x4 zc = {0.f, 0.f, 0.f, 0.f};

    f16x8 AwO[2][4], AXO[2], AfcO[4];
    float fcbv[4] = {};
    int cbase = 0;
    f16x8 own;

    // ---- encoder ----
    load_rnn_W(eWih, eWhh, ebih, ebhh, w, m, g, AwO, AXO);
    {
        const float* hp = h0p + (long)(b0 + m) * HH + wr_off;
        own = cvt8(*(const float4*)hp, *(const float4*)(hp + 4));
        *(f16x8*)&planes[0][m][wr_off] = own;
    }
    __syncthreads();

    const float* xrow = enc_in + (long)(b0 + m) * TT * NI + 8 * g;
    float* outp = out + (long)(b0 + m) * TT * NC;

    {
        float4 xa0, xa1, xb0, xb1;
        load_xe(xrow, g, xa0, xa1);
        load_xe(xrow + NI, g, xb0, xb1);
        for (int t = 0; t < TT; t += 2) {
            STEPE(0, xa0, xa1, t, 0);
            STEPE(1, xb0, xb1, t + 1, 0);
        }
    }
    // h_T now in own (regs) + planes[0]

    // ---- decoder ----
    load_rnn_W(dWih, dWhh, dbih, dbhh, w, m, g, AwO, AXO);

    if (XP) {
        _Float16* xh = hws + (long)(b0 + m) * TT * HH + wr_off;
        f16x8 xq0 = *(const f16x8*)(xh + 0 * HH);
        f16x8 xq1 = *(const f16x8*)(xh + 1 * HH);
        f16x8 xq2 = *(const f16x8*)(xh + 2 * HH);
        f16x8 xq3 = *(const f16x8*)(xh + 3 * HH);
        for (int t = 0; t < TT; t += 4) {
            STEPD(0, xq0, t);
            STEPD(1, xq1, t + 1);
            STEPD(0, xq2, t + 2);
            STEPD(1, xq3, t + 3);
        }
        // FC handled by fc_kernel from the h dump
    } else {
        if (w >= 2) {
            const int ct = w - 2;
            cbase = 16 * ct + 4 * g;
            const int c = 16 * ct + m;
#pragma unroll
            for (int k = 0; k < 4; ++k) {
                const int s = (w + k) & 3;
                f16x8 a;
#pragma unroll
                for (int e = 0; e < 8; ++e) {
                    int kk = 32 * s + 8 * g + e;
                    a[e] = (c < NC) ? (_Float16)fcW[c * HH + kk] : (_Float16)0.f;
                }
                AfcO[k] = a;
            }
#pragma unroll
            for (int q = 0; q < 4; ++q) {
                int c2 = cbase + q;
                fcbv[q] = (c2 < NC) ? fcb[c2] : 0.f;
            }
        }
        xrow = dec_in + (long)(b0 + m) * TT * NI + 8 * g;
        float4 xa0, xa1, xb0, xb1;
        load_xe(xrow, g, xa0, xa1);
        load_xe(xrow + NI, g, xb0, xb1);
        for (int t = 0; t < TT; t += 2) {
            STEPE(0, xa0, xa1, t, 1);
            STEPE(1, xb0, xb1, t + 1, 1);
        }
        // epilogue FC for t = TT-1 (h_T in planes[0] + own)
        if (w >= 2) {
            f16x8 rd0 = *(const f16x8*)&planes[0][m][rb1];
            f16x8 rd1 = *(const f16x8*)&planes[0][m][rb2];
            f16x8 rd2 = *(const f16x8*)&planes[0][m][rb3];
            f32x4 f0 = MFMA16(AfcO[0], own, zc);
            f0 = MFMA16(AfcO[1], rd0, f0);
            f0 = MFMA16(AfcO[2], rd1, f0);
            f0 = MFMA16(AfcO[3], rd2, f0);
            float* op = outp + (long)(TT - 1) * NC + cbase;
#pragma unroll
            for (int q = 0; q < 4; ++q)
                if (cbase + q < NC) op[q] = f0[q] + fcbv[q];
        }
    }
}

extern "C" void kernel_launch(void* const* d_in, const int* in_sizes, int n_in,
                              void* d_out, int out_size, void* d_ws, size_t ws_size,
                              hipStream_t stream) {
    const float* enc_in  = (const float*)d_in[0];
    const float* enc_h0  = (const float*)d_in[1];
    const float* dec_in  = (const float*)d_in[2];
    const float* enc_Wih = (const float*)d_in[3];
    const float* enc_Whh = (const float*)d_in[4];
    const float* enc_bih = (const float*)d_in[5];
    const float* enc_bhh = (const float*)d_in[6];
    const float* dec_Wih = (const float*)d_in[7];
    const float* dec_Whh = (const float*)d_in[8];
    const float* dec_bih = (const float*)d_in[9];
    const float* dec_bhh = (const float*)d_in[10];
    const float* fc_W    = (const float*)d_in[11];
    const float* fc_b    = (const float*)d_in[12];
    float* out = (float*)d_out;

    dim3 grid(BB / ROWS), block(256);
    const bool fast = (ws_size >= (size_t)WS_NEED);

    if (fast) {
        _Float16* hws = (_Float16*)d_ws;
        dim3 xgrid((unsigned)(BT / 64)), xblock(256);
        xp_kernel<<<xgrid, xblock, 0, stream>>>(dec_in, dec_Wih, dec_bih, dec_bhh, hws);
        seq2seq_chain<1><<<grid, block, 0, stream>>>(enc_in, enc_h0, dec_in,
                                                     enc_Wih, enc_Whh, enc_bih, enc_bhh,
                                                     dec_Wih, dec_Whh, dec_bih, dec_bhh,
                                                     fc_W, fc_b, hws, out);
        fc_kernel<<<xgrid, xblock, 0, stream>>>(hws, fc_W, fc_b, out);
    } else {
        seq2seq_chain<0><<<grid, block, 0, stream>>>(enc_in, enc_h0, dec_in,
                                                     enc_Wih, enc_Whh, enc_bih, enc_bhh,
                                                     dec_Wih, dec_Whh, dec_bih, dec_bhh,
                                                     fc_W, fc_b, nullptr, out);
    }
}